// Round 6
// baseline (73.474 us; speedup 1.0000x reference)
//
#include <hip/hip_runtime.h>
#include <hip/hip_bf16.h>
#include <cstdint>
#include <cstddef>

#define N_NODES 8192
#define IN_DIM  128
#define OUT_DIM 64
#define LRELU_ALPHA 0.2f
#define LOG2E 1.44269504f
#define NSTEP 32            // super-steps of 256 j

using f32x16 = __attribute__((ext_vector_type(16))) float;
using bf16x8 = __attribute__((ext_vector_type(8))) short;

typedef const __attribute__((address_space(1))) int* gas_ptr;
typedef __attribute__((address_space(3))) int* las_ptr;

static __device__ __forceinline__ unsigned short f2bf(float x) {
    union { float f; unsigned u; } v; v.f = x;
    unsigned r = v.u + 0x7FFFu + ((v.u >> 16) & 1u);  // RNE (prep only)
    return (unsigned short)(r >> 16);
}

// ---------------------------------------------------------------------------
// K1: h = x@W ; svec = (h@a_src)*log2e ; dvec = (h@a_dst)*log2e ;
// hpack = bf16(h) in MFMA-B layout. Grid 1024 x 256thr, k-split over waves.
// ---------------------------------------------------------------------------
__global__ __launch_bounds__(256) void gat_prep(
    const float* __restrict__ x, const float* __restrict__ W,
    const float* __restrict__ a,
    float* __restrict__ svec, float* __restrict__ dvec,
    unsigned short* __restrict__ hpack)
{
    __shared__ float shA[4][8][64];
    const int tid = threadIdx.x;
    const int w   = tid >> 6;
    const int f   = tid & 63;
    const int i0  = blockIdx.x * 8;

    float acc[8];
#pragma unroll
    for (int r = 0; r < 8; ++r) acc[r] = 0.f;

    const int k0 = w * 32;
#pragma unroll 2
    for (int k = k0; k < k0 + 32; k += 4) {
        const float w0 = W[(k + 0) * OUT_DIM + f];
        const float w1 = W[(k + 1) * OUT_DIM + f];
        const float w2 = W[(k + 2) * OUT_DIM + f];
        const float w3 = W[(k + 3) * OUT_DIM + f];
#pragma unroll
        for (int r = 0; r < 8; ++r) {
            const float4 xv = *reinterpret_cast<const float4*>(
                x + (size_t)(i0 + r) * IN_DIM + k);
            acc[r] = fmaf(xv.x, w0, acc[r]);
            acc[r] = fmaf(xv.y, w1, acc[r]);
            acc[r] = fmaf(xv.z, w2, acc[r]);
            acc[r] = fmaf(xv.w, w3, acc[r]);
        }
    }
#pragma unroll
    for (int r = 0; r < 8; ++r) shA[w][r][f] = acc[r];
    __syncthreads();

    if (w == 0) {
        union { unsigned short us[8]; int4 v; } pk;
#pragma unroll
        for (int r = 0; r < 8; ++r) {
            const float hv = shA[0][r][f] + shA[1][r][f] + shA[2][r][f] + shA[3][r][f];
            pk.us[r] = f2bf(hv);
        }
        const int jb    = i0 >> 4;
        const int jhalf = (i0 >> 3) & 1;
        const int fb    = f >> 5;
        const int lidx  = (f & 31) + 32 * jhalf;
        *reinterpret_cast<int4*>(hpack + ((size_t)(jb * 2 + fb) * 64 + lidx) * 8) = pk.v;
    } else if (w == 1) {
        const float asrc = a[f];
#pragma unroll
        for (int r = 0; r < 8; ++r) {
            const float hv = shA[0][r][f] + shA[1][r][f] + shA[2][r][f] + shA[3][r][f];
            float sv = hv * asrc;
#pragma unroll
            for (int off = 32; off >= 1; off >>= 1) sv += __shfl_xor(sv, off);
            if (f == 0) svec[i0 + r] = sv * LOG2E;
        }
    } else if (w == 2) {
        const float adst = a[OUT_DIM + f];
#pragma unroll
        for (int r = 0; r < 8; ++r) {
            const float hv = shA[0][r][f] + shA[1][r][f] + shA[2][r][f] + shA[3][r][f];
            float dv = hv * adst;
#pragma unroll
            for (int off = 32; off >= 1; off >>= 1) dv += __shfl_xor(dv, off);
            if (f == 0) dvec[i0 + r] = dv * LOG2E;
        }
    }
}

// ---------------------------------------------------------------------------
// K2: full-row single pass. Grid 256 x 512thr (8 waves, 1 block/CU).
// Block = 32 rows x ALL 8192 j; wave w owns j-window w*1024. Super-step =
// 32 rows x 256 j staged to LDS (32 insts, 1 row x 1KB contiguous each,
// XOR-swizzled both sides); each wave computes its 32-j subrange (2 MFMA
// k-steps). Counted vmcnt + raw barriers (queue never drains mid-loop;
// final iteration peeled to vmcnt(8) - fixes round-5's latent race).
// Epilogue: LDS-reduce 8 waves, normalize, ELU, write fp32 out directly.
// No partial buffers, no third kernel.
// ---------------------------------------------------------------------------
__global__ __launch_bounds__(512, 2) void gat_main(
    const int* __restrict__ adj,
    const float* __restrict__ svec, const float* __restrict__ dvec,
    const unsigned short* __restrict__ hpack,
    float* __restrict__ out)
{
    union SH {
        int tiles[2][32 * 256];                                  // 2 x 32KB adj
        struct { float red[8][32][64]; float redden[8][32]; } r; // 65KB
    };
    __shared__ SH sh;

    const int tid = threadIdx.x;
    const int w   = tid >> 6;        // 0..7
    const int l   = tid & 63;
    const int rb  = blockIdx.x;
    const int row = l & 31;          // A-fragment row (query i within block)
    const int kh  = l >> 5;          // k-half
    const int i0  = rb * 32;

    const float s_i = svec[i0 + row];   // already * log2e
    asm volatile("" :: "v"(s_i));        // completed before staging begins
    const bf16x8* hp = reinterpret_cast<const bf16x8*>(hpack);

    // stage 32 rows x 256 j (32KB): per wave 4 insts, 1 row x 1KB contiguous,
    // 16B-unit column XOR-swizzled on the GLOBAL side (cg = l ^ (row&7)).
    auto stage = [&](int buf, int ss) {
        const int jt0 = ss * 256;
#pragma unroll
        for (int q = 0; q < 4; ++q) {
            const int r0 = w * 4 + q;                 // tile row 0..31
            const int cg = l ^ (r0 & 7);              // 16B unit, swizzled
            const int* gsrc = adj + (size_t)(i0 + r0) * N_NODES + jt0 + cg * 4;
            int* ldst = &sh.tiles[buf][r0 * 256];     // wave-uniform base
            __builtin_amdgcn_global_load_lds((gas_ptr)gsrc, (las_ptr)ldst, 16, 0, 0);
        }
    };

    f32x16 acc0, acc1;
#pragma unroll
    for (int r = 0; r < 16; ++r) { acc0[r] = 0.f; acc1[r] = 0.f; }
    float den = 0.f;

    stage(0, 0);
    stage(1, 1);

    const int swz = row & 7;
    for (int s = 0; s < NSTEP; ++s) {
        const int buf = s & 1;
        const int jg  = s * 256 + w * 32;   // wave's 32-j subrange this step
        const int jb  = jg >> 4;

        // ---- plain loads (L2-hit) for this step's compute: issue FIRST ----
        const bf16x8 b00 = hp[(jb * 2 + 0) * 64 + l];
        const bf16x8 b01 = hp[(jb * 2 + 1) * 64 + l];
        const bf16x8 b10 = hp[(jb * 2 + 2) * 64 + l];
        const bf16x8 b11 = hp[(jb * 2 + 3) * 64 + l];
        const int j0 = jg + kh * 8;
        const float4 dA0 = *reinterpret_cast<const float4*>(dvec + j0);
        const float4 dA1 = *reinterpret_cast<const float4*>(dvec + j0 + 4);
        const float4 dB0 = *reinterpret_cast<const float4*>(dvec + j0 + 16);
        const float4 dB1 = *reinterpret_cast<const float4*>(dvec + j0 + 20);

        // newest outstanding = plains(8) [+ stage(s+1)(4) except last iter]
        if (s == NSTEP - 1) asm volatile("s_waitcnt vmcnt(8)"  ::: "memory");
        else                asm volatile("s_waitcnt vmcnt(12)" ::: "memory");
        __builtin_amdgcn_s_barrier();     // all waves' stage(s) visible

        // ---- adj reads from LDS (both k-steps), un-swizzle on read ----
        const int* tb = &sh.tiles[buf][0];
        const int c00 = w * 8 + kh * 2;
        const int c10 = w * 8 + 4 + kh * 2;
        const int4 A00 = *reinterpret_cast<const int4*>(&tb[row * 256 + ((c00    ) ^ swz) * 4]);
        const int4 A01 = *reinterpret_cast<const int4*>(&tb[row * 256 + ((c00 + 1) ^ swz) * 4]);
        const int4 A10 = *reinterpret_cast<const int4*>(&tb[row * 256 + ((c10    ) ^ swz) * 4]);
        const int4 A11 = *reinterpret_cast<const int4*>(&tb[row * 256 + ((c10 + 1) ^ swz) * 4]);
        asm volatile("s_waitcnt lgkmcnt(0)" ::: "memory");  // reads landed in regs
        __builtin_amdgcn_s_barrier();     // all waves done reading buf

        // overwrite of buf now safe: stage two steps ahead
        if (s + 2 < NSTEP) stage(buf, s + 2);

        // ---- compute (registers only) ----
        const float dd0[8] = {dA0.x, dA0.y, dA0.z, dA0.w, dA1.x, dA1.y, dA1.z, dA1.w};
        const int   ia0[8] = {A00.x, A00.y, A00.z, A00.w, A01.x, A01.y, A01.z, A01.w};
        const float dd1[8] = {dB0.x, dB0.y, dB0.z, dB0.w, dB1.x, dB1.y, dB1.z, dB1.w};
        const int   ia1[8] = {A10.x, A10.y, A10.z, A10.w, A11.x, A11.y, A11.z, A11.w};

        bf16x8 af0, af1;
#pragma unroll
        for (int e = 0; e < 8; ++e) {
            float ev = s_i + dd0[e];
            ev = fmaxf(ev, LRELU_ALPHA * ev);
            float pv = __builtin_amdgcn_exp2f(ev);
            pv = (ia0[e] > 0) ? pv : 0.f;
            union { float f; unsigned u; } pu; pu.f = pv;
            pu.u &= 0xFFFF0000u;
            den += pu.f;
            af0[e] = (short)(pu.u >> 16);
        }
#pragma unroll
        for (int e = 0; e < 8; ++e) {
            float ev = s_i + dd1[e];
            ev = fmaxf(ev, LRELU_ALPHA * ev);
            float pv = __builtin_amdgcn_exp2f(ev);
            pv = (ia1[e] > 0) ? pv : 0.f;
            union { float f; unsigned u; } pu; pu.f = pv;
            pu.u &= 0xFFFF0000u;
            den += pu.f;
            af1[e] = (short)(pu.u >> 16);
        }
        acc0 = __builtin_amdgcn_mfma_f32_32x32x16_bf16(af0, b00, acc0, 0, 0, 0);
        acc1 = __builtin_amdgcn_mfma_f32_32x32x16_bf16(af0, b01, acc1, 0, 0, 0);
        acc0 = __builtin_amdgcn_mfma_f32_32x32x16_bf16(af1, b10, acc0, 0, 0, 0);
        acc1 = __builtin_amdgcn_mfma_f32_32x32x16_bf16(af1, b11, acc1, 0, 0, 0);
    }

    __syncthreads();   // full drain; union becomes the reduction buffer

    // scatter acc via verified C/D layout: col=l&31, row=(r&3)+8*(r>>2)+4*kh
#pragma unroll
    for (int r = 0; r < 16; ++r) {
        const int orow = (r & 3) + 8 * (r >> 2) + 4 * kh;
        sh.r.red[w][orow][row]      = acc0[r];
        sh.r.red[w][orow][32 + row] = acc1[r];
    }
    const float dtot = den + __shfl_xor(den, 32);   // combine kh halves
    if (l < 32) sh.r.redden[w][l] = dtot;
    __syncthreads();

    // reduce 8 waves, normalize, ELU, write out directly
    for (int e = tid; e < 32 * 64; e += 512) {
        const int orow = e >> 6;
        float v = 0.f, dsum = 0.f;
#pragma unroll
        for (int ww = 0; ww < 8; ++ww) {
            v    += sh.r.red[ww][orow][e & 63];
            dsum += sh.r.redden[ww][orow];
        }
        const float o = v / dsum;
        out[(size_t)(i0 + orow) * OUT_DIM + (e & 63)] = (o > 0.f) ? o : expm1f(o);
    }
}

extern "C" void kernel_launch(void* const* d_in, const int* in_sizes, int n_in,
                              void* d_out, int out_size, void* d_ws, size_t ws_size,
                              hipStream_t stream)
{
    const float* x   = (const float*)d_in[0];
    const int*   adj = (const int*)d_in[1];
    const float* W   = (const float*)d_in[2];
    const float* a   = (const float*)d_in[3];
    float* out = (float*)d_out;

    float* svec = (float*)d_ws;                                  // 8192 f32
    float* dvec = svec + N_NODES;                                // 8192 f32
    unsigned short* hpack = (unsigned short*)(dvec + N_NODES);   // 1 MB bf16

    gat_prep<<<N_NODES / 8, 256, 0, stream>>>(x, W, a, svec, dvec, hpack);
    gat_main<<<256, 512, 0, stream>>>(adj, svec, dvec, hpack, out);
}